// Round 5
// baseline (28.211 us; speedup 1.0000x reference)
//
#include <hip/hip_runtime.h>

// CTRMultiEmbedding: joint embedding gather + bilinear interval embedding.
// out = [joint (B,L,D) | delta (B,L,L,D)] concatenated, float32.
// delta[b,i,j,d] = base[m][d] + ds*cs[m][d] + dt*ct[m][d]
//   m = (i<len_b && j<len_b); base = e_sl+e_tl, cs = e_su-e_sl, ct = e_tu-e_tl.
//
// Round 5: HBM write-stream locality. Previous rounds (27-29 us, ~5.1 TB/s)
// had 8192 waves writing scattered 1-KB chunks -> row-buffer thrash.
// fillBuffer (long sequential runs/wave, low occupancy) hits 6.8 TB/s.
// Here: 1024 blocks x 256 = 4096 waves; wave w writes delta f4 span
// [w*2048, (w+1)*2048) SEQUENTIALLY (32 x 1-KB contiguous wave-stores).
// Batch index is wave-invariant (2048 | 2^20) -> len hoisted; mat read
// exactly once, sequentially; coefficients in 6 f4 registers (d-offset is
// lane-invariant). Joint output = one extra iteration on the first 512
// waves. Plain stores (NT regressed 2.5x in round 2).

typedef float f4 __attribute__((ext_vector_type(4)));
typedef float f2 __attribute__((ext_vector_type(2)));

constexpr int HOURS   = 168;
constexpr int Dd      = 64;
constexpr int NJOINT4 = 8 * 256 * 64 / 4;   // 32768 f4 (joint region)
constexpr int NJOINT  = NJOINT4 * 4;
constexpr int PER_WAVE = 2048;              // f4 per wave in delta region
constexpr int ITERS    = PER_WAVE / 64;     // 32

__device__ __forceinline__ f4 ld4(const float* p) {
    return *reinterpret_cast<const f4*>(p);
}

__global__ __launch_bounds__(256) void ctr_fused_kernel(
    const int*   __restrict__ traj,     // (B,L,3) int32
    const float* __restrict__ mat,      // (B,L,L,2)
    const int*   __restrict__ lens,     // (B)
    const float* __restrict__ emb_t,    // (169,64)
    const float* __restrict__ emb_l,    // (50000,64)
    const float* __restrict__ emb_u,    // (10000,64)
    const float* __restrict__ emb_su,   // (2,64)
    const float* __restrict__ emb_sl,
    const float* __restrict__ emb_tu,
    const float* __restrict__ emb_tl,
    float* __restrict__ out)
{
    const int tid  = threadIdx.x;
    const int wave = blockIdx.x * 4 + (tid >> 6);   // 0 .. 4095
    const int lane = tid & 63;
    const int g0   = wave * PER_WAVE + lane;        // f4 index in delta space
    const int d4f  = (lane & 15) * 4;               // float offset in D (lane-invariant)

    // ---- coefficients -> 6 f4 registers (1.5 KB tables, L1-broadcast) ----
    f4 sl0 = ld4(emb_sl + d4f), sl1 = ld4(emb_sl + 64 + d4f);
    f4 su0 = ld4(emb_su + d4f), su1 = ld4(emb_su + 64 + d4f);
    f4 tl0 = ld4(emb_tl + d4f), tl1 = ld4(emb_tl + 64 + d4f);
    f4 tu0 = ld4(emb_tu + d4f), tu1 = ld4(emb_tu + 64 + d4f);
    const f4 base0 = sl0 + tl0, base1 = sl1 + tl1;
    const f4 cs0   = su0 - sl0, cs1   = su1 - sl1;
    const f4 ct0   = tu0 - tl0, ct1   = tu1 - tl1;

    // ---- joint embedding: first 512 waves, one iteration each ----
    if (wave < NJOINT4 / 64) {
        int jidx = wave * 64 + lane;               // f4 index in joint region
        int row  = jidx >> 4;                      // 16-lane shared row
        int user = traj[row * 3 + 0];
        int loc  = traj[row * 3 + 1];
        int t    = traj[row * 3 + 2];
        int tm = (t - 1) % HOURS;                  // python modulo fixup
        if (tm < 0) tm += HOURS;
        int tx = tm + 1;
        f4 o = ld4(emb_t + tx * Dd + d4f)
             + ld4(emb_l + loc * Dd + d4f)
             + ld4(emb_u + user * Dd + d4f);
        *reinterpret_cast<f4*>(&out[(size_t)jidx * 4]) = o;
    }

    // ---- delta: batch index is wave-invariant -> hoist len ----
    const int b   = g0 >> 20;                      // 2^20 f4 per batch
    const int len = lens[b];

#pragma unroll 8
    for (int k = 0; k < ITERS; ++k) {
        int idx  = g0 + k * 64;                    // f4 index in delta space
        int pair = idx >> 4;                       // b*65536 + i*256 + j
        int i    = (pair >> 8) & 255;
        int j    = pair & 255;
        bool v   = (i < len) && (j < len);
        f2 dd = *reinterpret_cast<const f2*>(&mat[(size_t)pair * 2]);
        f4 ba = v ? base1 : base0;
        f4 ca = v ? cs1   : cs0;
        f4 ta = v ? ct1   : ct0;
        f4 o = ba + dd.x * ca + dd.y * ta;
        *reinterpret_cast<f4*>(&out[NJOINT + (size_t)idx * 4]) = o;
    }
}

extern "C" void kernel_launch(void* const* d_in, const int* in_sizes, int n_in,
                              void* d_out, int out_size, void* d_ws, size_t ws_size,
                              hipStream_t stream) {
    const int*   traj   = (const int*)  d_in[0];
    const float* mat    = (const float*)d_in[1];
    const int*   lens   = (const int*)  d_in[2];
    const float* emb_t  = (const float*)d_in[3];
    const float* emb_l  = (const float*)d_in[4];
    const float* emb_u  = (const float*)d_in[5];
    const float* emb_su = (const float*)d_in[6];
    const float* emb_sl = (const float*)d_in[7];
    const float* emb_tu = (const float*)d_in[8];
    const float* emb_tl = (const float*)d_in[9];
    float* out = (float*)d_out;

    ctr_fused_kernel<<<1024, 256, 0, stream>>>(
        traj, mat, lens, emb_t, emb_l, emb_u, emb_su, emb_sl, emb_tu, emb_tl, out);
}